// Round 13
// baseline (749.717 us; speedup 1.0000x reference)
//
#include <hip/hip_runtime.h>
#include <stdint.h>

#define M_DIM 2048
#define K_DIM 4096
#define N_DIM 11008

typedef int v4i  __attribute__((ext_vector_type(4)));
typedef int v16i __attribute__((ext_vector_type(16)));

// ---------------- workspace layout ----------------
// xq_packed: [mblk=16][kt=64][u=512]x16B  (8 MB)  fragment-ordered
// wt_packed: [nblk=43][kt=64][u=1024]x16B (45 MB)
#define WS_XQ_OFF   65536ull
#define WS_WT_OFF   8454144ull
#define WS_FULL_BYTES (8454144ull + 45088768ull)
#define WS_SMALL_BYTES 8454144ull

static __device__ __forceinline__ void llds16(const void* g, void* l) {
  __builtin_amdgcn_global_load_lds(
      reinterpret_cast<const uint32_t __attribute__((address_space(1)))*>(
          reinterpret_cast<uintptr_t>(g)),
      reinterpret_cast<uint32_t __attribute__((address_space(3)))*>(
          reinterpret_cast<uintptr_t>(l)),
      16, 0, 0);
}

// ---------------- kernel 1: per-block abs-max over x ----------------
__global__ __launch_bounds__(256) void absmax_kernel(const float* __restrict__ x,
                                                     float* __restrict__ part) {
  __shared__ float red[256];
  const int g = blockIdx.x * 256 + threadIdx.x;
  const float4* x4 = reinterpret_cast<const float4*>(x);
  float m = 0.f;
#pragma unroll
  for (int i = 0; i < 8; ++i) {
    float4 v = x4[(size_t)i * 262144 + g];
    m = fmaxf(m, fmaxf(fmaxf(fabsf(v.x), fabsf(v.y)),
                       fmaxf(fabsf(v.z), fabsf(v.w))));
  }
  red[threadIdx.x] = m;
  __syncthreads();
  for (int s = 128; s > 0; s >>= 1) {
    if (threadIdx.x < s) red[threadIdx.x] = fmaxf(red[threadIdx.x], red[threadIdx.x + s]);
    __syncthreads();
  }
  if (threadIdx.x == 0) part[blockIdx.x] = red[0];
}

// ---------------- kernel 2: finalize scales ----------------
__global__ __launch_bounds__(256) void finalize_scale(const float* __restrict__ part,
                                                      const float* __restrict__ y_scale,
                                                      float* __restrict__ scales) {
  __shared__ float red[256];
  const int t = threadIdx.x;
  float m = fmaxf(fmaxf(part[t], part[t + 256]), fmaxf(part[t + 512], part[t + 768]));
  red[t] = m;
  __syncthreads();
  for (int s = 128; s > 0; s >>= 1) {
    if (t < s) red[t] = fmaxf(red[t], red[t + s]);
    __syncthreads();
  }
  if (t == 0) {
    float xs = red[0] * (1.0f / 128.0f);  // exact (pow2)
    scales[0] = xs;
    scales[1] = xs * y_scale[0];
  }
}

static __device__ __forceinline__ int quant4(float4 v, float s) {
  int q0 = (int)rintf(v.x / s);  // matches np.round (half-to-even)
  int q1 = (int)rintf(v.y / s);
  int q2 = (int)rintf(v.z / s);
  int q3 = (int)rintf(v.w / s);
  q0 = max(-128, min(127, q0));
  q1 = max(-128, min(127, q1));
  q2 = max(-128, min(127, q2));
  q3 = max(-128, min(127, q3));
  return (q0 & 255) | ((q1 & 255) << 8) | ((q2 & 255) << 16) | ((q3 & 255) << 24);
}

// ---------------- kernel 3a: quantize x -> xq_packed (fragment order) --------
// Unit u (16B) within [mblk][kt]: u = (rowgrp<<7)|(kstep<<6)|(khalf<<5)|row32.
__global__ __launch_bounds__(256) void quant_pack(const float* __restrict__ x,
                                                  const float* __restrict__ scales,
                                                  signed char* __restrict__ xq) {
  const float s = scales[0];
  const int g = blockIdx.x * 256 + threadIdx.x;   // unit id, 524288 total
  const int mblk = g >> 15;
  const int kt = (g >> 9) & 63;
  const int u = g & 511;
  const int row = mblk * 128 + ((u >> 7) & 3) * 32 + (u & 31);
  const int kf = kt * 64 + ((u >> 6) & 1) * 32 + ((u >> 5) & 1) * 16;
  const float4* xp = reinterpret_cast<const float4*>(x + (size_t)row * K_DIM + kf);
  v4i o;
#pragma unroll
  for (int i = 0; i < 4; ++i) o[i] = quant4(xp[i], s);
  *reinterpret_cast<v4i*>(xq + (size_t)g * 16) = o;
}

// ---------------- kernel 3b: row-major quant (fallback path only) ------------
__global__ __launch_bounds__(256) void quant_rowmajor(const float* __restrict__ x,
                                                      const float* __restrict__ scales,
                                                      signed char* __restrict__ xq) {
  const float s = scales[0];
  const size_t t = (size_t)blockIdx.x * 256 + threadIdx.x;
  const float4* x4 = reinterpret_cast<const float4*>(x) + t * 4;
  v4i o;
#pragma unroll
  for (int i = 0; i < 4; ++i) o[i] = quant4(x4[i], s);
  *reinterpret_cast<v4i*>(xq + t * 16) = o;
}

// ---------------- kernel 4: transpose+pack w32[K,N] -> wt_packed --------------
// Unit u within [nblk][kt]: u = (ngrp<<7)|(kstep<<6)|(khalf<<5)|n32.
__global__ __launch_bounds__(256) void transpose_pack(const int* __restrict__ w,
                                                      signed char* __restrict__ wt) {
  __shared__ int tile[64 * 65];  // [k][n], pad 65
  const int t = threadIdx.x;
  const int bx = blockIdx.x;          // n-tile (64 cols)
  const int by = blockIdx.y;          // k-tile (64 rows)
  const int n0 = bx * 64;
  const int k0 = by * 64;
#pragma unroll
  for (int p = 0; p < 4; ++p) {
    const int id = p * 256 + t;
    const int r = id >> 4;
    const int c4 = id & 15;
    v4i v = *reinterpret_cast<const v4i*>(w + (size_t)(k0 + r) * N_DIM + n0 + c4 * 4);
    tile[r * 65 + c4 * 4 + 0] = v[0];
    tile[r * 65 + c4 * 4 + 1] = v[1];
    tile[r * 65 + c4 * 4 + 2] = v[2];
    tile[r * 65 + c4 * 4 + 3] = v[3];
  }
  __syncthreads();
  const int nl = ((t >> 7) << 5) | (t & 31);
  const int kc = (t >> 5) & 3;
  v4i o;
#pragma unroll
  for (int q = 0; q < 4; ++q) {
    const int kb = kc * 16 + q * 4;
    int b0 = tile[(kb + 0) * 65 + nl] & 255;
    int b1 = tile[(kb + 1) * 65 + nl] & 255;
    int b2 = tile[(kb + 2) * 65 + nl] & 255;
    int b3 = tile[(kb + 3) * 65 + nl] & 255;
    o[q] = b0 | (b1 << 8) | (b2 << 16) | (b3 << 24);
  }
  const size_t base = ((size_t)(bx >> 2) * 64 + by) * 16384;   // [nblk][kt]
  const int ubase = ((bx & 3) * 2) << 7;                        // ngrp_base*128
  *reinterpret_cast<v4i*>(wt + base + (size_t)(ubase + t) * 16) = o;
}

// ---------------- kernel 5: int8 MFMA GEMM v12 (R8 body @ 3 blocks/CU) --------
// BM=128, BN=256, BK=64 bytes. 512 threads = 8 waves (2M x 4N), wave-tile
// 64x64 via 2x2 frags of mfma_i32_32x32x32_i8 — R8's refcheck-proven body.
// Change vs R8: ring-2 x 24KB = 48KB LDS -> 3 blocks/CU (144KB), so the
// 688-block grid is SINGLE-ROUND (makespan 3/2.69 = 89.6% vs 67% at 2/CU),
// and 6 waves/SIMD of cross-block mixing hide the per-iter vmcnt(0) drain
// (T3 minimum-2-phase recipe: STAGE issued BEFORE compute covers load lat).
#define V12_TILE_B 24576          // A 8KB + B 16KB
#define V12_NT     (K_DIM / 64)   // 64 K-tiles

__global__ __launch_bounds__(512, 6) void gemm_i8_v12(
    const signed char* __restrict__ xq, const signed char* __restrict__ wt,
    const float* __restrict__ scales, const float* __restrict__ bias,
    float* __restrict__ y) {
  __shared__ __align__(16) signed char smem[2 * V12_TILE_B];  // 48 KB
  const int tid = threadIdx.x;

  // T1: bijective XCD swizzle (688 blocks = 8 x 86), column-major grid
  // (16 consecutive swz share one 1MB wt n-panel in L2).
  const int bid = blockIdx.x;
  const int swz = (bid & 7) * 86 + (bid >> 3);
  const int mblk = swz & 15;        // 16 m-tiles of 128
  const int nblk = swz >> 4;        // 43 n-tiles of 256
  const int m0 = mblk * 128;
  const int n0 = nblk * 256;

  // staging: fragment-packed global source, contiguous per (blk, kt).
  const signed char* gA = xq + (size_t)mblk * 64 * 8192;    // + kt*8192  + tid*16
  const signed char* gB = wt + (size_t)nblk * 64 * 16384;   // + kt*16384 + tid*16 (+8192)
  signed char* const ld = smem + tid * 16;

#define STAGE(kt, soff)                                                   \
  do {                                                                    \
    llds16(gA + (size_t)(kt) * 8192 + tid * 16,         ld + (soff));     \
    llds16(gB + (size_t)(kt) * 16384 + tid * 16,        ld + (soff) + 8192);  \
    llds16(gB + (size_t)(kt) * 16384 + 8192 + tid * 16, ld + (soff) + 16384); \
  } while (0)

  // fragment map (R8 refcheck-proven): frag (grp, ks) at grp*2048 + ks*1024
  // + lane*16  (A: grp = wm*2+fa in [0,4); B: grp = wn*2+fb in [0,8)).
  const int lane = tid & 63;
  const int wid = tid >> 6;
  const int wm = wid >> 2;   // 0..1
  const int wn = wid & 3;    // 0..3
  const int aoff = (wm * 2) * 2048 + lane * 16;
  const int boff = 8192 + (wn * 2) * 2048 + lane * 16;

  v16i acc[2][2] = {};

#define COMPUTE(roff)                                                         \
  do {                                                                        \
    const signed char* bp_ = smem + (roff);                                   \
    _Pragma("unroll")                                                         \
    for (int ks_ = 0; ks_ < 2; ++ks_) {                                       \
      v4i a0 = *reinterpret_cast<const v4i*>(bp_ + aoff + ks_ * 1024);        \
      v4i a1 = *reinterpret_cast<const v4i*>(bp_ + aoff + 2048 + ks_ * 1024); \
      v4i b0 = *reinterpret_cast<const v4i*>(bp_ + boff + ks_ * 1024);        \
      v4i b1 = *reinterpret_cast<const v4i*>(bp_ + boff + 2048 + ks_ * 1024); \
      acc[0][0] = __builtin_amdgcn_mfma_i32_32x32x32_i8(a0, b0, acc[0][0], 0, 0, 0); \
      acc[0][1] = __builtin_amdgcn_mfma_i32_32x32x32_i8(a0, b1, acc[0][1], 0, 0, 0); \
      acc[1][0] = __builtin_amdgcn_mfma_i32_32x32x32_i8(a1, b0, acc[1][0], 0, 0, 0); \
      acc[1][1] = __builtin_amdgcn_mfma_i32_32x32x32_i8(a1, b1, acc[1][1], 0, 0, 0); \
    }                                                                         \
  } while (0)

  // prologue: stage tile 0 into buf0, drain once.
  STAGE(0, 0);
  asm volatile("s_waitcnt vmcnt(0)" ::: "memory");
  __builtin_amdgcn_s_barrier();

  // main loop (T3 minimum 2-phase): issue next-tile STAGE before compute;
  // one vmcnt(0)+barrier per tile. Unrolled x2 so LDS offsets are immediates.
  for (int t = 0; t < V12_NT - 2; t += 2) {
    STAGE(t + 1, V12_TILE_B);        // load hides under COMPUTE below
    COMPUTE(0);
    asm volatile("s_waitcnt vmcnt(0)" ::: "memory");
    __builtin_amdgcn_s_barrier();    // buf1 ready; buf0 free (reads consumed)
    STAGE(t + 2, 0);
    COMPUTE(V12_TILE_B);
    asm volatile("s_waitcnt vmcnt(0)" ::: "memory");
    __builtin_amdgcn_s_barrier();
  }
  // t = 62 in buf0: stage 63, compute 62, gate, compute 63.
  STAGE(V12_NT - 1, V12_TILE_B);
  COMPUTE(0);
  asm volatile("s_waitcnt vmcnt(0)" ::: "memory");
  __builtin_amdgcn_s_barrier();
  COMPUTE(V12_TILE_B);

#undef STAGE
#undef COMPUTE

  // epilogue: 32x32 C/D layout col=lane&31, row=(reg&3)+8*(reg>>2)+4*(lane>>5)
  // [measured m74/m101; R8 refcheck-passed]
  const float s = scales[1];
  const int l31 = lane & 31;
  const int lh4 = (lane >> 5) * 4;
#pragma unroll
  for (int fb = 0; fb < 2; ++fb) {
    const int col = n0 + wn * 64 + fb * 32 + l31;
    const float bv = bias[col];
#pragma unroll
    for (int fa = 0; fa < 2; ++fa) {
      const int rbase = m0 + wm * 64 + fa * 32 + lh4;
#pragma unroll
      for (int reg = 0; reg < 16; ++reg) {
        const int row = rbase + (reg & 3) + 8 * (reg >> 2);
        y[(size_t)row * N_DIM + col] = (float)acc[fa][fb][reg] * s + bv;
      }
    }
  }
}

// ---------------- fallback (small ws): sdot4 LDS GEMM reading w32 ----------------
#if defined(__has_builtin)
#if __has_builtin(__builtin_amdgcn_sdot4)
#define HAVE_SDOT4 1
#endif
#endif

static __device__ __forceinline__ int dot4(int a, int b, int c) {
#ifdef HAVE_SDOT4
  return __builtin_amdgcn_sdot4(a, b, c, false);
#else
  c += (int)(signed char)(a) * (int)(signed char)(b);
  c += (int)(signed char)(a >> 8) * (int)(signed char)(b >> 8);
  c += (int)(signed char)(a >> 16) * (int)(signed char)(b >> 16);
  c += (int)(signed char)(a >> 24) * (int)(signed char)(b >> 24);
  return c;
#endif
}

__global__ __launch_bounds__(256) void gemm_fallback(
    const signed char* __restrict__ xq, const int* __restrict__ w,
    const float* __restrict__ scales, const float* __restrict__ bias,
    float* __restrict__ y) {
  __shared__ int lds_a[64 * 17];
  __shared__ int lds_b[64 * 17];
  const int t = threadIdx.x;
  const int m0 = blockIdx.y * 64;
  const int n0 = blockIdx.x * 64;
  const int my = (t >> 4) * 4;
  const int nx = (t & 15) * 4;
  int acc[4][4] = {};
  for (int kt = 0; kt < K_DIM / 64; ++kt) {
    const int k0 = kt * 64;
    {
      const int r = t >> 2, sg = t & 3;
      v4i v = *reinterpret_cast<const v4i*>(xq + (size_t)(m0 + r) * K_DIM + k0 + sg * 16);
      lds_a[r * 17 + sg * 4 + 0] = v[0];
      lds_a[r * 17 + sg * 4 + 1] = v[1];
      lds_a[r * 17 + sg * 4 + 2] = v[2];
      lds_a[r * 17 + sg * 4 + 3] = v[3];
    }
    {
      const int n = t & 63, bkk = (t >> 6) * 4;
#pragma unroll
      for (int q = 0; q < 4; ++q) {
        const int kk = bkk + q;
        int b0 = w[(size_t)(k0 + kk * 4 + 0) * N_DIM + n0 + n] & 255;
        int b1 = w[(size_t)(k0 + kk * 4 + 1) * N_DIM + n0 + n] & 255;
        int b2 = w[(size_t)(k0 + kk * 4 + 2) * N_DIM + n0 + n] & 255;
        int b3 = w[(size_t)(k0 + kk * 4 + 3) * N_DIM + n0 + n] & 255;
        lds_b[n * 17 + kk] = b0 | (b1 << 8) | (b2 << 16) | (b3 << 24);
      }
    }
    __syncthreads();
#pragma unroll
    for (int kk = 0; kk < 16; ++kk) {
      int a[4], b[4];
#pragma unroll
      for (int i = 0; i < 4; ++i) a[i] = lds_a[(my + i) * 17 + kk];
#pragma unroll
      for (int j = 0; j < 4; ++j) b[j] = lds_b[(nx + j) * 17 + kk];
#pragma unroll
      for (int i = 0; i < 4; ++i)
#pragma unroll
        for (int j = 0; j < 4; ++j) acc[i][j] = dot4(a[i], b[j], acc[i][j]);
    }
    __syncthreads();
  }
  const float s = scales[1];
#pragma unroll
  for (int i = 0; i < 4; ++i)
#pragma unroll
    for (int j = 0; j < 4; ++j)
      y[(size_t)(m0 + my + i) * N_DIM + n0 + nx + j] =
          (float)acc[i][j] * s + bias[n0 + nx + j];
}

// ---------------- launcher ----------------
extern "C" void kernel_launch(void* const* d_in, const int* in_sizes, int n_in,
                              void* d_out, int out_size, void* d_ws, size_t ws_size,
                              hipStream_t stream) {
  (void)in_sizes; (void)n_in; (void)out_size;
  const float* x = (const float*)d_in[0];
  const int* w = (const int*)d_in[1];  // int8 values stored as int32
  const float* bias = (const float*)d_in[2];
  const float* yscale = (const float*)d_in[3];
  float* y = (float*)d_out;
  char* ws = (char*)d_ws;
  float* scales = (float*)(ws);
  float* part = (float*)(ws + 1024);
  signed char* xq = (signed char*)(ws + WS_XQ_OFF);
  signed char* wt = (signed char*)(ws + WS_WT_OFF);

  if (ws_size < WS_SMALL_BYTES) return;

  absmax_kernel<<<1024, 256, 0, stream>>>(x, part);
  finalize_scale<<<1, 256, 0, stream>>>(part, yscale, scales);
  if (ws_size >= WS_FULL_BYTES) {
    quant_pack<<<2048, 256, 0, stream>>>(x, scales, xq);
    transpose_pack<<<dim3(N_DIM / 64, K_DIM / 64), 256, 0, stream>>>(w, wt);
    gemm_i8_v12<<<(M_DIM / 128) * (N_DIM / 256), 512, 0, stream>>>(xq, wt, scales, bias, y);
  } else {
    quant_rowmajor<<<2048, 256, 0, stream>>>(x, scales, xq);
    gemm_fallback<<<dim3(N_DIM / 64, M_DIM / 64), 256, 0, stream>>>(xq, w, scales, bias, y);
  }
}

// Round 14
// 176.089 us; speedup vs baseline: 4.2576x; 4.2576x over previous
//
#include <hip/hip_runtime.h>
#include <stdint.h>

#define M_DIM 2048
#define K_DIM 4096
#define N_DIM 11008

typedef int v4i  __attribute__((ext_vector_type(4)));
typedef int v16i __attribute__((ext_vector_type(16)));

// ---------------- workspace layout ----------------
// xq_packed: [mblk=16][kt=64][u=512]x16B  (8 MB)  fragment-ordered
// wt_packed: [nblk=43][kt=64][u=1024]x16B (45 MB)
#define WS_XQ_OFF   65536ull
#define WS_WT_OFF   8454144ull
#define WS_FULL_BYTES (8454144ull + 45088768ull)
#define WS_SMALL_BYTES 8454144ull

static __device__ __forceinline__ void llds16(const void* g, void* l) {
  __builtin_amdgcn_global_load_lds(
      reinterpret_cast<const uint32_t __attribute__((address_space(1)))*>(
          reinterpret_cast<uintptr_t>(g)),
      reinterpret_cast<uint32_t __attribute__((address_space(3)))*>(
          reinterpret_cast<uintptr_t>(l)),
      16, 0, 0);
}

// ---------------- kernel 1: per-block abs-max over x ----------------
__global__ __launch_bounds__(256) void absmax_kernel(const float* __restrict__ x,
                                                     float* __restrict__ part) {
  __shared__ float red[256];
  const int g = blockIdx.x * 256 + threadIdx.x;
  const float4* x4 = reinterpret_cast<const float4*>(x);
  float m = 0.f;
#pragma unroll
  for (int i = 0; i < 8; ++i) {
    float4 v = x4[(size_t)i * 262144 + g];
    m = fmaxf(m, fmaxf(fmaxf(fabsf(v.x), fabsf(v.y)),
                       fmaxf(fabsf(v.z), fabsf(v.w))));
  }
  red[threadIdx.x] = m;
  __syncthreads();
  for (int s = 128; s > 0; s >>= 1) {
    if (threadIdx.x < s) red[threadIdx.x] = fmaxf(red[threadIdx.x], red[threadIdx.x + s]);
    __syncthreads();
  }
  if (threadIdx.x == 0) part[blockIdx.x] = red[0];
}

// ---------------- kernel 2: finalize scales ----------------
__global__ __launch_bounds__(256) void finalize_scale(const float* __restrict__ part,
                                                      const float* __restrict__ y_scale,
                                                      float* __restrict__ scales) {
  __shared__ float red[256];
  const int t = threadIdx.x;
  float m = fmaxf(fmaxf(part[t], part[t + 256]), fmaxf(part[t + 512], part[t + 768]));
  red[t] = m;
  __syncthreads();
  for (int s = 128; s > 0; s >>= 1) {
    if (t < s) red[t] = fmaxf(red[t], red[t + s]);
    __syncthreads();
  }
  if (t == 0) {
    float xs = red[0] * (1.0f / 128.0f);  // exact (pow2)
    scales[0] = xs;
    scales[1] = xs * y_scale[0];
  }
}

static __device__ __forceinline__ int quant4(float4 v, float s) {
  int q0 = (int)rintf(v.x / s);  // matches np.round (half-to-even)
  int q1 = (int)rintf(v.y / s);
  int q2 = (int)rintf(v.z / s);
  int q3 = (int)rintf(v.w / s);
  q0 = max(-128, min(127, q0));
  q1 = max(-128, min(127, q1));
  q2 = max(-128, min(127, q2));
  q3 = max(-128, min(127, q3));
  return (q0 & 255) | ((q1 & 255) << 8) | ((q2 & 255) << 16) | ((q3 & 255) << 24);
}

// ---------------- kernel 3a: quantize x -> xq_packed (fragment order) --------
// Unit u (16B) within [mblk][kt]: u = (rowgrp<<7)|(kstep<<6)|(khalf<<5)|row32.
__global__ __launch_bounds__(256) void quant_pack(const float* __restrict__ x,
                                                  const float* __restrict__ scales,
                                                  signed char* __restrict__ xq) {
  const float s = scales[0];
  const int g = blockIdx.x * 256 + threadIdx.x;   // unit id, 524288 total
  const int mblk = g >> 15;
  const int kt = (g >> 9) & 63;
  const int u = g & 511;
  const int row = mblk * 128 + ((u >> 7) & 3) * 32 + (u & 31);
  const int kf = kt * 64 + ((u >> 6) & 1) * 32 + ((u >> 5) & 1) * 16;
  const float4* xp = reinterpret_cast<const float4*>(x + (size_t)row * K_DIM + kf);
  v4i o;
#pragma unroll
  for (int i = 0; i < 4; ++i) o[i] = quant4(xp[i], s);
  *reinterpret_cast<v4i*>(xq + (size_t)g * 16) = o;
}

// ---------------- kernel 3b: row-major quant (fallback path only) ------------
__global__ __launch_bounds__(256) void quant_rowmajor(const float* __restrict__ x,
                                                      const float* __restrict__ scales,
                                                      signed char* __restrict__ xq) {
  const float s = scales[0];
  const size_t t = (size_t)blockIdx.x * 256 + threadIdx.x;
  const float4* x4 = reinterpret_cast<const float4*>(x) + t * 4;
  v4i o;
#pragma unroll
  for (int i = 0; i < 4; ++i) o[i] = quant4(x4[i], s);
  *reinterpret_cast<v4i*>(xq + t * 16) = o;
}

// ---------------- kernel 4: transpose+pack w32[K,N] -> wt_packed --------------
// Unit u within [nblk][kt]: u = (ngrp<<7)|(kstep<<6)|(khalf<<5)|n32.
__global__ __launch_bounds__(256) void transpose_pack(const int* __restrict__ w,
                                                      signed char* __restrict__ wt) {
  __shared__ int tile[64 * 65];  // [k][n], pad 65
  const int t = threadIdx.x;
  const int bx = blockIdx.x;          // n-tile (64 cols)
  const int by = blockIdx.y;          // k-tile (64 rows)
  const int n0 = bx * 64;
  const int k0 = by * 64;
#pragma unroll
  for (int p = 0; p < 4; ++p) {
    const int id = p * 256 + t;
    const int r = id >> 4;
    const int c4 = id & 15;
    v4i v = *reinterpret_cast<const v4i*>(w + (size_t)(k0 + r) * N_DIM + n0 + c4 * 4);
    tile[r * 65 + c4 * 4 + 0] = v[0];
    tile[r * 65 + c4 * 4 + 1] = v[1];
    tile[r * 65 + c4 * 4 + 2] = v[2];
    tile[r * 65 + c4 * 4 + 3] = v[3];
  }
  __syncthreads();
  const int nl = ((t >> 7) << 5) | (t & 31);
  const int kc = (t >> 5) & 3;
  v4i o;
#pragma unroll
  for (int q = 0; q < 4; ++q) {
    const int kb = kc * 16 + q * 4;
    int b0 = tile[(kb + 0) * 65 + nl] & 255;
    int b1 = tile[(kb + 1) * 65 + nl] & 255;
    int b2 = tile[(kb + 2) * 65 + nl] & 255;
    int b3 = tile[(kb + 3) * 65 + nl] & 255;
    o[q] = b0 | (b1 << 8) | (b2 << 16) | (b3 << 24);
  }
  const size_t base = ((size_t)(bx >> 2) * 64 + by) * 16384;   // [nblk][kt]
  const int ubase = ((bx & 3) * 2) << 7;                        // ngrp_base*128
  *reinterpret_cast<v4i*>(wt + base + (size_t)(ubase + t) * 16) = o;
}

// ---------------- kernel 5: int8 MFMA GEMM v13 (R9 body @ 3 blocks/CU) --------
// BM=128, BN=256, BK=64 bytes. 256 threads = 4 waves (2M x 2N), wave-tile
// 64x128 via 2x4 frags of mfma_i32_32x32x32_i8 — R9's refcheck-proven body
// (VGPR 108; fits 3 waves/SIMD budget 170, unlike R13's 8-wave spill).
// Ring-2 x 24KB = 48KB LDS -> 3 blocks/CU: the 688-block grid runs in a
// SINGLE round (89.6% grid-eff vs 67% at 2 blk/CU) with 12 waves/CU mixing.
// Loop = T3 minimum 2-phase: STAGE(next) issued BEFORE COMPUTE(cur), one
// vmcnt(0)+barrier per K-tile (m230/m248: 2-phase ~= 92% of 8-phase).
#define V13_TILE_B 24576          // A 8KB + B 16KB
#define V13_NT     (K_DIM / 64)   // 64 K-tiles

__global__ __launch_bounds__(256, 3) void gemm_i8_v13(
    const signed char* __restrict__ xq, const signed char* __restrict__ wt,
    const float* __restrict__ scales, const float* __restrict__ bias,
    float* __restrict__ y) {
  __shared__ __align__(16) signed char smem[2 * V13_TILE_B];  // 48 KB
  const int tid = threadIdx.x;

  // T1: bijective XCD swizzle (688 blocks = 8 x 86), column-major grid.
  const int bid = blockIdx.x;
  const int swz = (bid & 7) * 86 + (bid >> 3);
  const int mblk = swz & 15;        // 16 m-tiles of 128
  const int nblk = swz >> 4;        // 43 n-tiles of 256
  const int m0 = mblk * 128;
  const int n0 = nblk * 256;

  // staging: fragment-packed global source, contiguous per (blk, kt).
  const signed char* gA = xq + (size_t)mblk * 64 * 8192;    // + kt*8192
  const signed char* gB = wt + (size_t)nblk * 64 * 16384;   // + kt*16384
  signed char* const ld = smem + tid * 16;   // 256 thr x 16B = 4KB stripes

#define STAGE(kt, soff)                                                       \
  do {                                                                        \
    const size_t a_ = (size_t)(kt) * 8192 + tid * 16;                         \
    const size_t b_ = (size_t)(kt) * 16384 + tid * 16;                        \
    llds16(gA + a_,         ld + (soff));                                     \
    llds16(gA + a_ + 4096,  ld + (soff) + 4096);                              \
    llds16(gB + b_,         ld + (soff) + 8192);                              \
    llds16(gB + b_ + 4096,  ld + (soff) + 12288);                             \
    llds16(gB + b_ + 8192,  ld + (soff) + 16384);                             \
    llds16(gB + b_ + 12288, ld + (soff) + 20480);                             \
  } while (0)

  // fragment map (R9 refcheck-proven): frag grp at grp*2048 + ks*1024 + lane*16.
  // A: grp = wm*2 + fa (fa 0..1); B: grp = wn*4 + fb (fb 0..3).
  const int lane = tid & 63;
  const int wid = tid >> 6;
  const int wm = wid >> 1;   // 0..1 -> 64-row half of 128
  const int wn = wid & 1;    // 0..1 -> 128-col half of 256
  const int aoff = (wm * 2) * 2048 + lane * 16;
  const int boff = 8192 + (wn * 4) * 2048 + lane * 16;

  v16i acc[2][4] = {};

#define COMPUTE(roff)                                                          \
  do {                                                                         \
    const signed char* bp_ = smem + (roff);                                    \
    _Pragma("unroll")                                                          \
    for (int ks_ = 0; ks_ < 2; ++ks_) {                                        \
      v4i a0 = *reinterpret_cast<const v4i*>(bp_ + aoff + ks_ * 1024);         \
      v4i a1 = *reinterpret_cast<const v4i*>(bp_ + aoff + 2048 + ks_ * 1024);  \
      v4i b0 = *reinterpret_cast<const v4i*>(bp_ + boff + ks_ * 1024);         \
      v4i b1 = *reinterpret_cast<const v4i*>(bp_ + boff + 2048 + ks_ * 1024);  \
      v4i b2 = *reinterpret_cast<const v4i*>(bp_ + boff + 4096 + ks_ * 1024);  \
      v4i b3 = *reinterpret_cast<const v4i*>(bp_ + boff + 6144 + ks_ * 1024);  \
      acc[0][0] = __builtin_amdgcn_mfma_i32_32x32x32_i8(a0, b0, acc[0][0], 0, 0, 0); \
      acc[0][1] = __builtin_amdgcn_mfma_i32_32x32x32_i8(a0, b1, acc[0][1], 0, 0, 0); \
      acc[0][2] = __builtin_amdgcn_mfma_i32_32x32x32_i8(a0, b2, acc[0][2], 0, 0, 0); \
      acc[0][3] = __builtin_amdgcn_mfma_i32_32x32x32_i8(a0, b3, acc[0][3], 0, 0, 0); \
      acc[1][0] = __builtin_amdgcn_mfma_i32_32x32x32_i8(a1, b0, acc[1][0], 0, 0, 0); \
      acc[1][1] = __builtin_amdgcn_mfma_i32_32x32x32_i8(a1, b1, acc[1][1], 0, 0, 0); \
      acc[1][2] = __builtin_amdgcn_mfma_i32_32x32x32_i8(a1, b2, acc[1][2], 0, 0, 0); \
      acc[1][3] = __builtin_amdgcn_mfma_i32_32x32x32_i8(a1, b3, acc[1][3], 0, 0, 0); \
    }                                                                          \
  } while (0)

  // prologue: stage tile 0 into buf0, drain once.
  STAGE(0, 0);
  asm volatile("s_waitcnt vmcnt(0)" ::: "memory");
  __builtin_amdgcn_s_barrier();

  // main loop: STAGE(next, other buf) before COMPUTE(cur); unrolled x2 so
  // all LDS offsets are immediates. One vmcnt(0)+barrier per K-tile.
  for (int t = 0; t < V13_NT - 2; t += 2) {
    STAGE(t + 1, V13_TILE_B);        // 6 loads hide under 16 MFMA below
    COMPUTE(0);
    asm volatile("s_waitcnt vmcnt(0)" ::: "memory");
    __builtin_amdgcn_s_barrier();
    STAGE(t + 2, 0);
    COMPUTE(V13_TILE_B);
    asm volatile("s_waitcnt vmcnt(0)" ::: "memory");
    __builtin_amdgcn_s_barrier();
  }
  // tile 62 in buf0: stage 63, compute 62, gate, compute 63.
  STAGE(V13_NT - 1, V13_TILE_B);
  COMPUTE(0);
  asm volatile("s_waitcnt vmcnt(0)" ::: "memory");
  __builtin_amdgcn_s_barrier();
  COMPUTE(V13_TILE_B);

#undef STAGE
#undef COMPUTE

  // epilogue: 32x32 C/D layout col=lane&31, row=(reg&3)+8*(reg>>2)+4*(lane>>5)
  // [measured m74/m101; R8/R9 refcheck-passed]
  const float s = scales[1];
  const int l31 = lane & 31;
  const int lh4 = (lane >> 5) * 4;
#pragma unroll
  for (int fb = 0; fb < 4; ++fb) {
    const int col = n0 + wn * 128 + fb * 32 + l31;
    const float bv = bias[col];
#pragma unroll
    for (int fa = 0; fa < 2; ++fa) {
      const int rbase = m0 + wm * 64 + fa * 32 + lh4;
#pragma unroll
      for (int reg = 0; reg < 16; ++reg) {
        const int row = rbase + (reg & 3) + 8 * (reg >> 2);
        y[(size_t)row * N_DIM + col] = (float)acc[fa][fb][reg] * s + bv;
      }
    }
  }
}

// ---------------- fallback (small ws): sdot4 LDS GEMM reading w32 ----------------
#if defined(__has_builtin)
#if __has_builtin(__builtin_amdgcn_sdot4)
#define HAVE_SDOT4 1
#endif
#endif

static __device__ __forceinline__ int dot4(int a, int b, int c) {
#ifdef HAVE_SDOT4
  return __builtin_amdgcn_sdot4(a, b, c, false);
#else
  c += (int)(signed char)(a) * (int)(signed char)(b);
  c += (int)(signed char)(a >> 8) * (int)(signed char)(b >> 8);
  c += (int)(signed char)(a >> 16) * (int)(signed char)(b >> 16);
  c += (int)(signed char)(a >> 24) * (int)(signed char)(b >> 24);
  return c;
#endif
}

__global__ __launch_bounds__(256) void gemm_fallback(
    const signed char* __restrict__ xq, const int* __restrict__ w,
    const float* __restrict__ scales, const float* __restrict__ bias,
    float* __restrict__ y) {
  __shared__ int lds_a[64 * 17];
  __shared__ int lds_b[64 * 17];
  const int t = threadIdx.x;
  const int m0 = blockIdx.y * 64;
  const int n0 = blockIdx.x * 64;
  const int my = (t >> 4) * 4;
  const int nx = (t & 15) * 4;
  int acc[4][4] = {};
  for (int kt = 0; kt < K_DIM / 64; ++kt) {
    const int k0 = kt * 64;
    {
      const int r = t >> 2, sg = t & 3;
      v4i v = *reinterpret_cast<const v4i*>(xq + (size_t)(m0 + r) * K_DIM + k0 + sg * 16);
      lds_a[r * 17 + sg * 4 + 0] = v[0];
      lds_a[r * 17 + sg * 4 + 1] = v[1];
      lds_a[r * 17 + sg * 4 + 2] = v[2];
      lds_a[r * 17 + sg * 4 + 3] = v[3];
    }
    {
      const int n = t & 63, bkk = (t >> 6) * 4;
#pragma unroll
      for (int q = 0; q < 4; ++q) {
        const int kk = bkk + q;
        int b0 = w[(size_t)(k0 + kk * 4 + 0) * N_DIM + n0 + n] & 255;
        int b1 = w[(size_t)(k0 + kk * 4 + 1) * N_DIM + n0 + n] & 255;
        int b2 = w[(size_t)(k0 + kk * 4 + 2) * N_DIM + n0 + n] & 255;
        int b3 = w[(size_t)(k0 + kk * 4 + 3) * N_DIM + n0 + n] & 255;
        lds_b[n * 17 + kk] = b0 | (b1 << 8) | (b2 << 16) | (b3 << 24);
      }
    }
    __syncthreads();
#pragma unroll
    for (int kk = 0; kk < 16; ++kk) {
      int a[4], b[4];
#pragma unroll
      for (int i = 0; i < 4; ++i) a[i] = lds_a[(my + i) * 17 + kk];
#pragma unroll
      for (int j = 0; j < 4; ++j) b[j] = lds_b[(nx + j) * 17 + kk];
#pragma unroll
      for (int i = 0; i < 4; ++i)
#pragma unroll
        for (int j = 0; j < 4; ++j) acc[i][j] = dot4(a[i], b[j], acc[i][j]);
    }
    __syncthreads();
  }
  const float s = scales[1];
#pragma unroll
  for (int i = 0; i < 4; ++i)
#pragma unroll
    for (int j = 0; j < 4; ++j)
      y[(size_t)(m0 + my + i) * N_DIM + n0 + nx + j] =
          (float)acc[i][j] * s + bias[n0 + nx + j];
}

// ---------------- launcher ----------------
extern "C" void kernel_launch(void* const* d_in, const int* in_sizes, int n_in,
                              void* d_out, int out_size, void* d_ws, size_t ws_size,
                              hipStream_t stream) {
  (void)in_sizes; (void)n_in; (void)out_size;
  const float* x = (const float*)d_in[0];
  const int* w = (const int*)d_in[1];  // int8 values stored as int32
  const float* bias = (const float*)d_in[2];
  const float* yscale = (const float*)d_in[3];
  float* y = (float*)d_out;
  char* ws = (char*)d_ws;
  float* scales = (float*)(ws);
  float* part = (float*)(ws + 1024);
  signed char* xq = (signed char*)(ws + WS_XQ_OFF);
  signed char* wt = (signed char*)(ws + WS_WT_OFF);

  if (ws_size < WS_SMALL_BYTES) return;

  absmax_kernel<<<1024, 256, 0, stream>>>(x, part);
  finalize_scale<<<1, 256, 0, stream>>>(part, yscale, scales);
  if (ws_size >= WS_FULL_BYTES) {
    quant_pack<<<2048, 256, 0, stream>>>(x, scales, xq);
    transpose_pack<<<dim3(N_DIM / 64, K_DIM / 64), 256, 0, stream>>>(w, wt);
    gemm_i8_v13<<<(M_DIM / 128) * (N_DIM / 256), 256, 0, stream>>>(xq, wt, scales, bias, y);
  } else {
    quant_rowmajor<<<2048, 256, 0, stream>>>(x, scales, xq);
    gemm_fallback<<<dim3(N_DIM / 64, M_DIM / 64), 256, 0, stream>>>(xq, w, scales, bias, y);
  }
}

// Round 15
// 158.933 us; speedup vs baseline: 4.7172x; 1.1079x over previous
//
#include <hip/hip_runtime.h>
#include <stdint.h>

#define M_DIM 2048
#define K_DIM 4096
#define N_DIM 11008

typedef int v4i  __attribute__((ext_vector_type(4)));
typedef int v16i __attribute__((ext_vector_type(16)));

// ---------------- workspace layout ----------------
// xq_packed: [mblk=16][kt=64][u=512]x16B  (8 MB)  fragment-ordered
// wt_packed: [nblk=43][kt=64][u=1024]x16B (45 MB)
#define WS_XQ_OFF   65536ull
#define WS_WT_OFF   8454144ull
#define WS_FULL_BYTES (8454144ull + 45088768ull)
#define WS_SMALL_BYTES 8454144ull

static __device__ __forceinline__ void llds16(const void* g, void* l) {
  __builtin_amdgcn_global_load_lds(
      reinterpret_cast<const uint32_t __attribute__((address_space(1)))*>(
          reinterpret_cast<uintptr_t>(g)),
      reinterpret_cast<uint32_t __attribute__((address_space(3)))*>(
          reinterpret_cast<uintptr_t>(l)),
      16, 0, 0);
}

// ---------------- kernel 1: per-block abs-max over x ----------------
__global__ __launch_bounds__(256) void absmax_kernel(const float* __restrict__ x,
                                                     float* __restrict__ part) {
  __shared__ float red[256];
  const int g = blockIdx.x * 256 + threadIdx.x;
  const float4* x4 = reinterpret_cast<const float4*>(x);
  float m = 0.f;
#pragma unroll
  for (int i = 0; i < 8; ++i) {
    float4 v = x4[(size_t)i * 262144 + g];
    m = fmaxf(m, fmaxf(fmaxf(fabsf(v.x), fabsf(v.y)),
                       fmaxf(fabsf(v.z), fabsf(v.w))));
  }
  red[threadIdx.x] = m;
  __syncthreads();
  for (int s = 128; s > 0; s >>= 1) {
    if (threadIdx.x < s) red[threadIdx.x] = fmaxf(red[threadIdx.x], red[threadIdx.x + s]);
    __syncthreads();
  }
  if (threadIdx.x == 0) part[blockIdx.x] = red[0];
}

// ---------------- kernel 2: finalize scales ----------------
__global__ __launch_bounds__(256) void finalize_scale(const float* __restrict__ part,
                                                      const float* __restrict__ y_scale,
                                                      float* __restrict__ scales) {
  __shared__ float red[256];
  const int t = threadIdx.x;
  float m = fmaxf(fmaxf(part[t], part[t + 256]), fmaxf(part[t + 512], part[t + 768]));
  red[t] = m;
  __syncthreads();
  for (int s = 128; s > 0; s >>= 1) {
    if (t < s) red[t] = fmaxf(red[t], red[t + s]);
    __syncthreads();
  }
  if (t == 0) {
    float xs = red[0] * (1.0f / 128.0f);  // exact (pow2)
    scales[0] = xs;
    scales[1] = xs * y_scale[0];
  }
}

static __device__ __forceinline__ int quant4(float4 v, float s) {
  int q0 = (int)rintf(v.x / s);  // matches np.round (half-to-even)
  int q1 = (int)rintf(v.y / s);
  int q2 = (int)rintf(v.z / s);
  int q3 = (int)rintf(v.w / s);
  q0 = max(-128, min(127, q0));
  q1 = max(-128, min(127, q1));
  q2 = max(-128, min(127, q2));
  q3 = max(-128, min(127, q3));
  return (q0 & 255) | ((q1 & 255) << 8) | ((q2 & 255) << 16) | ((q3 & 255) << 24);
}

// ---------------- kernel 3a: quantize x -> xq_packed (fragment order) --------
// Unit u (16B) within [mblk][kt]: u = (rowgrp<<7)|(kstep<<6)|(khalf<<5)|row32.
__global__ __launch_bounds__(256) void quant_pack(const float* __restrict__ x,
                                                  const float* __restrict__ scales,
                                                  signed char* __restrict__ xq) {
  const float s = scales[0];
  const int g = blockIdx.x * 256 + threadIdx.x;   // unit id, 524288 total
  const int mblk = g >> 15;
  const int kt = (g >> 9) & 63;
  const int u = g & 511;
  const int row = mblk * 128 + ((u >> 7) & 3) * 32 + (u & 31);
  const int kf = kt * 64 + ((u >> 6) & 1) * 32 + ((u >> 5) & 1) * 16;
  const float4* xp = reinterpret_cast<const float4*>(x + (size_t)row * K_DIM + kf);
  v4i o;
#pragma unroll
  for (int i = 0; i < 4; ++i) o[i] = quant4(xp[i], s);
  *reinterpret_cast<v4i*>(xq + (size_t)g * 16) = o;
}

// ---------------- kernel 3b: row-major quant (fallback path only) ------------
__global__ __launch_bounds__(256) void quant_rowmajor(const float* __restrict__ x,
                                                      const float* __restrict__ scales,
                                                      signed char* __restrict__ xq) {
  const float s = scales[0];
  const size_t t = (size_t)blockIdx.x * 256 + threadIdx.x;
  const float4* x4 = reinterpret_cast<const float4*>(x) + t * 4;
  v4i o;
#pragma unroll
  for (int i = 0; i < 4; ++i) o[i] = quant4(x4[i], s);
  *reinterpret_cast<v4i*>(xq + t * 16) = o;
}

// ---------------- kernel 4: transpose+pack w32[K,N] -> wt_packed --------------
// Unit u within [nblk][kt]: u = (ngrp<<7)|(kstep<<6)|(khalf<<5)|n32.
__global__ __launch_bounds__(256) void transpose_pack(const int* __restrict__ w,
                                                      signed char* __restrict__ wt) {
  __shared__ int tile[64 * 65];  // [k][n], pad 65
  const int t = threadIdx.x;
  const int bx = blockIdx.x;          // n-tile (64 cols)
  const int by = blockIdx.y;          // k-tile (64 rows)
  const int n0 = bx * 64;
  const int k0 = by * 64;
#pragma unroll
  for (int p = 0; p < 4; ++p) {
    const int id = p * 256 + t;
    const int r = id >> 4;
    const int c4 = id & 15;
    v4i v = *reinterpret_cast<const v4i*>(w + (size_t)(k0 + r) * N_DIM + n0 + c4 * 4);
    tile[r * 65 + c4 * 4 + 0] = v[0];
    tile[r * 65 + c4 * 4 + 1] = v[1];
    tile[r * 65 + c4 * 4 + 2] = v[2];
    tile[r * 65 + c4 * 4 + 3] = v[3];
  }
  __syncthreads();
  const int nl = ((t >> 7) << 5) | (t & 31);
  const int kc = (t >> 5) & 3;
  v4i o;
#pragma unroll
  for (int q = 0; q < 4; ++q) {
    const int kb = kc * 16 + q * 4;
    int b0 = tile[(kb + 0) * 65 + nl] & 255;
    int b1 = tile[(kb + 1) * 65 + nl] & 255;
    int b2 = tile[(kb + 2) * 65 + nl] & 255;
    int b3 = tile[(kb + 3) * 65 + nl] & 255;
    o[q] = b0 | (b1 << 8) | (b2 << 16) | (b3 << 24);
  }
  const size_t base = ((size_t)(bx >> 2) * 64 + by) * 16384;   // [nblk][kt]
  const int ubase = ((bx & 3) * 2) << 7;                        // ngrp_base*128
  *reinterpret_cast<v4i*>(wt + base + (size_t)(ubase + t) * 16) = o;
}

// ---------------- kernel 5: int8 MFMA GEMM v8 (32x32x32, packed operands) -----
// [R8 — measured optimum of the family: GEMM ~100us, MfmaUtil 43%, twice
// reproduced. Family plateau: intrinsic(0.64) x grid(0.67) trade-space fully
// mapped (R7/R10/R14 corners all worse); breaking it needs hand-asm K-loop.]
// BM=128, BN=256, BK=64 bytes. 512 threads = 8 waves (2M x 4N), wave-tile
// 64x64 via 2x2 frags of mfma_i32_32x32x32_i8. Operands pre-packed in
// fragment order: staging is 3 contiguous global_load_lds / thread; all
// ds_read_b128 are base + lane*16 (conflict-free). Ring-3 x 24KB = 72KB
// -> 2 blk/CU. Depth-2 prefetch, vmcnt(3) once per K-tile (never 0 in loop).
#define V8_TILE_B 24576           // A 8KB + B 16KB
#define V8_NT     (K_DIM / 64)    // 64 K-tiles

__global__ __launch_bounds__(512, 4) void gemm_i8_v8(
    const signed char* __restrict__ xq, const signed char* __restrict__ wt,
    const float* __restrict__ scales, const float* __restrict__ bias,
    float* __restrict__ y) {
  __shared__ __align__(16) signed char smem[3 * V8_TILE_B];  // 72 KB
  const int tid = threadIdx.x;

  // T1: bijective XCD swizzle (688 blocks = 8 x 86), column-major grid.
  const int bid = blockIdx.x;
  const int swz = (bid & 7) * 86 + (bid >> 3);
  const int mblk = swz & 15;        // 16 m-tiles of 128
  const int nblk = swz >> 4;        // 43 n-tiles of 256
  const int m0 = mblk * 128;
  const int n0 = nblk * 256;

  // staging: fragment-packed global source, contiguous per (blk, kt).
  const signed char* gA = xq + (size_t)mblk * 64 * 8192;    // + kt*8192  + tid*16
  const signed char* gB = wt + (size_t)nblk * 64 * 16384;   // + kt*16384 + tid*16 (+8192)
  signed char* const ld = smem + tid * 16;

#define STAGE(kt, soff)                                                   \
  do {                                                                    \
    llds16(gA + (size_t)(kt) * 8192 + tid * 16,         ld + (soff));     \
    llds16(gB + (size_t)(kt) * 16384 + tid * 16,        ld + (soff) + 8192);  \
    llds16(gB + (size_t)(kt) * 16384 + 8192 + tid * 16, ld + (soff) + 16384); \
  } while (0)

  // fragment map: LDS image is unit-ordered; frag (grp, kstep) lives at
  // grp*2048 + kstep*1024 + lane*16  (A: grp = wm*2+fa in [0,4); B: wn*2+fb in [0,8)).
  const int lane = tid & 63;
  const int wid = tid >> 6;
  const int wm = wid >> 2;   // 0..1
  const int wn = wid & 3;    // 0..3
  const int aoff = (wm * 2) * 2048 + lane * 16;           // + fa*2048 + ks*1024
  const int boff = 8192 + (wn * 2) * 2048 + lane * 16;    // + fb*2048 + ks*1024

  v16i acc[2][2] = {};

#define COMPUTE(roff)                                                         \
  do {                                                                        \
    const signed char* bp_ = smem + (roff);                                   \
    _Pragma("unroll")                                                         \
    for (int ks_ = 0; ks_ < 2; ++ks_) {                                       \
      v4i a0 = *reinterpret_cast<const v4i*>(bp_ + aoff + ks_ * 1024);        \
      v4i a1 = *reinterpret_cast<const v4i*>(bp_ + aoff + 2048 + ks_ * 1024); \
      v4i b0 = *reinterpret_cast<const v4i*>(bp_ + boff + ks_ * 1024);        \
      v4i b1 = *reinterpret_cast<const v4i*>(bp_ + boff + 2048 + ks_ * 1024); \
      acc[0][0] = __builtin_amdgcn_mfma_i32_32x32x32_i8(a0, b0, acc[0][0], 0, 0, 0); \
      acc[0][1] = __builtin_amdgcn_mfma_i32_32x32x32_i8(a0, b1, acc[0][1], 0, 0, 0); \
      acc[1][0] = __builtin_amdgcn_mfma_i32_32x32x32_i8(a1, b0, acc[1][0], 0, 0, 0); \
      acc[1][1] = __builtin_amdgcn_mfma_i32_32x32x32_i8(a1, b1, acc[1][1], 0, 0, 0); \
    }                                                                         \
  } while (0)

  // prologue: stage tiles 0,1 (6 loads/thread in flight); retire tile 0.
  STAGE(0, 0);
  STAGE(1, V8_TILE_B);
  asm volatile("s_waitcnt vmcnt(3)" ::: "memory");
  __builtin_amdgcn_s_barrier();

  int rOff = 0;
  int sOff = 2 * V8_TILE_B;
  for (int t = 0; t < V8_NT - 2; ++t) {
    STAGE(t + 2, sOff);              // outstanding: t+1:3, t+2:3
    COMPUTE(rOff);                   // 8 ds_read_b128 + 8 MFMA (32x32x32)
    asm volatile("s_waitcnt vmcnt(3)" ::: "memory");  // retire tile t+1
    __builtin_amdgcn_s_barrier();
    rOff = (rOff == 2 * V8_TILE_B) ? 0 : rOff + V8_TILE_B;
    sOff = (sOff == 2 * V8_TILE_B) ? 0 : sOff + V8_TILE_B;
  }
  // t = NT-2: no staging; drain remaining tile
  COMPUTE(rOff);
  asm volatile("s_waitcnt vmcnt(0)" ::: "memory");
  __builtin_amdgcn_s_barrier();
  rOff = (rOff == 2 * V8_TILE_B) ? 0 : rOff + V8_TILE_B;
  // t = NT-1: final tile
  COMPUTE(rOff);

#undef STAGE
#undef COMPUTE

  // epilogue: 32x32 C/D layout col=lane&31, row=(reg&3)+8*(reg>>2)+4*(lane>>5)
  // [measured: m74/m101, dtype-independent; R8 refcheck-passed]
  const float s = scales[1];
  const int l31 = lane & 31;
  const int lh4 = (lane >> 5) * 4;
#pragma unroll
  for (int fb = 0; fb < 2; ++fb) {
    const int col = n0 + wn * 64 + fb * 32 + l31;
    const float bv = bias[col];
#pragma unroll
    for (int fa = 0; fa < 2; ++fa) {
      const int rbase = m0 + wm * 64 + fa * 32 + lh4;
#pragma unroll
      for (int reg = 0; reg < 16; ++reg) {
        const int row = rbase + (reg & 3) + 8 * (reg >> 2);
        y[(size_t)row * N_DIM + col] = (float)acc[fa][fb][reg] * s + bv;
      }
    }
  }
}

// ---------------- fallback (small ws): sdot4 LDS GEMM reading w32 ----------------
#if defined(__has_builtin)
#if __has_builtin(__builtin_amdgcn_sdot4)
#define HAVE_SDOT4 1
#endif
#endif

static __device__ __forceinline__ int dot4(int a, int b, int c) {
#ifdef HAVE_SDOT4
  return __builtin_amdgcn_sdot4(a, b, c, false);
#else
  c += (int)(signed char)(a) * (int)(signed char)(b);
  c += (int)(signed char)(a >> 8) * (int)(signed char)(b >> 8);
  c += (int)(signed char)(a >> 16) * (int)(signed char)(b >> 16);
  c += (int)(signed char)(a >> 24) * (int)(signed char)(b >> 24);
  return c;
#endif
}

__global__ __launch_bounds__(256) void gemm_fallback(
    const signed char* __restrict__ xq, const int* __restrict__ w,
    const float* __restrict__ scales, const float* __restrict__ bias,
    float* __restrict__ y) {
  __shared__ int lds_a[64 * 17];
  __shared__ int lds_b[64 * 17];
  const int t = threadIdx.x;
  const int m0 = blockIdx.y * 64;
  const int n0 = blockIdx.x * 64;
  const int my = (t >> 4) * 4;
  const int nx = (t & 15) * 4;
  int acc[4][4] = {};
  for (int kt = 0; kt < K_DIM / 64; ++kt) {
    const int k0 = kt * 64;
    {
      const int r = t >> 2, sg = t & 3;
      v4i v = *reinterpret_cast<const v4i*>(xq + (size_t)(m0 + r) * K_DIM + k0 + sg * 16);
      lds_a[r * 17 + sg * 4 + 0] = v[0];
      lds_a[r * 17 + sg * 4 + 1] = v[1];
      lds_a[r * 17 + sg * 4 + 2] = v[2];
      lds_a[r * 17 + sg * 4 + 3] = v[3];
    }
    {
      const int n = t & 63, bkk = (t >> 6) * 4;
#pragma unroll
      for (int q = 0; q < 4; ++q) {
        const int kk = bkk + q;
        int b0 = w[(size_t)(k0 + kk * 4 + 0) * N_DIM + n0 + n] & 255;
        int b1 = w[(size_t)(k0 + kk * 4 + 1) * N_DIM + n0 + n] & 255;
        int b2 = w[(size_t)(k0 + kk * 4 + 2) * N_DIM + n0 + n] & 255;
        int b3 = w[(size_t)(k0 + kk * 4 + 3) * N_DIM + n0 + n] & 255;
        lds_b[n * 17 + kk] = b0 | (b1 << 8) | (b2 << 16) | (b3 << 24);
      }
    }
    __syncthreads();
#pragma unroll
    for (int kk = 0; kk < 16; ++kk) {
      int a[4], b[4];
#pragma unroll
      for (int i = 0; i < 4; ++i) a[i] = lds_a[(my + i) * 17 + kk];
#pragma unroll
      for (int j = 0; j < 4; ++j) b[j] = lds_b[(nx + j) * 17 + kk];
#pragma unroll
      for (int i = 0; i < 4; ++i)
#pragma unroll
        for (int j = 0; j < 4; ++j) acc[i][j] = dot4(a[i], b[j], acc[i][j]);
    }
    __syncthreads();
  }
  const float s = scales[1];
#pragma unroll
  for (int i = 0; i < 4; ++i)
#pragma unroll
    for (int j = 0; j < 4; ++j)
      y[(size_t)(m0 + my + i) * N_DIM + n0 + nx + j] =
          (float)acc[i][j] * s + bias[n0 + nx + j];
}

// ---------------- launcher ----------------
extern "C" void kernel_launch(void* const* d_in, const int* in_sizes, int n_in,
                              void* d_out, int out_size, void* d_ws, size_t ws_size,
                              hipStream_t stream) {
  (void)in_sizes; (void)n_in; (void)out_size;
  const float* x = (const float*)d_in[0];
  const int* w = (const int*)d_in[1];  // int8 values stored as int32
  const float* bias = (const float*)d_in[2];
  const float* yscale = (const float*)d_in[3];
  float* y = (float*)d_out;
  char* ws = (char*)d_ws;
  float* scales = (float*)(ws);
  float* part = (float*)(ws + 1024);
  signed char* xq = (signed char*)(ws + WS_XQ_OFF);
  signed char* wt = (signed char*)(ws + WS_WT_OFF);

  if (ws_size < WS_SMALL_BYTES) return;

  absmax_kernel<<<1024, 256, 0, stream>>>(x, part);
  finalize_scale<<<1, 256, 0, stream>>>(part, yscale, scales);
  if (ws_size >= WS_FULL_BYTES) {
    quant_pack<<<2048, 256, 0, stream>>>(x, scales, xq);
    transpose_pack<<<dim3(N_DIM / 64, K_DIM / 64), 256, 0, stream>>>(w, wt);
    gemm_i8_v8<<<(M_DIM / 128) * (N_DIM / 256), 512, 0, stream>>>(xq, wt, scales, bias, y);
  } else {
    quant_rowmajor<<<2048, 256, 0, stream>>>(x, scales, xq);
    gemm_fallback<<<dim3(N_DIM / 64, M_DIM / 64), 256, 0, stream>>>(xq, w, scales, bias, y);
  }
}